// Round 3
// baseline (317.273 us; speedup 1.0000x reference)
//
#include <hip/hip_runtime.h>

// LBP semantic dependency, reduced channel-difference form:
//   d' = softplus(x + p) - softplus(x),  x = db - d_prev
//   db[a,u] = s_edge[n,u,a] + sum_{v != a,u} sum_t d'_t[a,u,v]
// R2 post-mortem: bound by scattered 128B/640B fetches at stride 102KB
// (~0.9 TB/s effective). Fix: one coalesced transpose pass materializes
// per-slice slabs R_t[n][a][v][u] (contiguous 100KB each); phase 1 (d1 sums)
// is fused into the transpose. Phases 2/3 read slab-local data (L2/L3-hot),
// with 23KB LDS -> 6 blocks/CU for latency hiding.

#define S    160
#define S2   (S*S)        // 25600
#define SLAB (S*S)        // floats per (n,a) slab of R
#define TSZ  (2*S*S*S)    // floats per reorganized tensor (8,192,000)

__device__ __forceinline__ float sp_f(float x) {
    // stable softplus (threshold 2e-2; fast-math flavor is plenty accurate)
    return fmaxf(x, 0.f) + __logf(1.f + __expf(-fabsf(x)));
}

// ---- kernel 0: db1 = edge  (db1[(n*S+a)*S+u] = s_edge[n][u][a])
__global__ __launch_bounds__(160)
void k_init(const float* __restrict__ s_edge, float* __restrict__ db1) {
    int a = blockIdx.x, n = blockIdx.y, u = threadIdx.x;
    db1[(n * S + a) * S + u] = s_edge[n * S2 + u * S + a];
}

// ---- kernel 1: gather-transpose s_t -> R_t[n][a][v][u], fused phase-1:
//      db1[n,a,u] += sum_{v != a,u} sum_t (sp(p_t(v,u)) - ln2)
__global__ __launch_bounds__(256)
void k_transpose(const float* __restrict__ s_sib,
                 const float* __restrict__ s_cop,
                 const float* __restrict__ s_grd,
                 float* __restrict__ r_sib,
                 float* __restrict__ r_cop,
                 float* __restrict__ r_grd,
                 float* __restrict__ db1) {
    const float LN2 = 0.6931471805599453f;
    int a0 = blockIdx.x * 8, v0 = blockIdx.y * 8, n = blockIdx.z;
    int tid = threadIdx.x;
    __shared__ float tile[8 * 8 * S];   // [vv][aa][u], 40 KB
    float acc[5] = {0.f, 0.f, 0.f, 0.f, 0.f};

    for (int t = 0; t < 3; ++t) {
        const float* sT = (t == 0) ? s_sib : (t == 1) ? s_cop : s_grd;
        float*       rT = (t == 0) ? r_sib : (t == 1) ? r_cop : r_grd;
        __syncthreads();   // protect previous tile
        // stage in: rows (v0+vv): s[n][v][a0:a0+8][0:160] = 5120 B contiguous
        {
            const float4* g = (const float4*)(sT + ((long)(n * S + v0) * S + a0) * S);
            float4* tf = (float4*)tile;
            #pragma unroll
            for (int kk = 0; kk < 10; ++kk) {
                int e  = kk * 256 + tid;     // 0..2559 float4s
                int vv = e / 320, c = e - vv * 320;
                tf[e] = g[(long)vv * 6400 + c];
            }
        }
        __syncthreads();
        // write out: per aa, R[n][a0+aa][v0:v0+8][:] = 5120 B contiguous
        {
            float4* rf = (float4*)rT;
            const float4* tf = (const float4*)tile;
            #pragma unroll
            for (int kk = 0; kk < 10; ++kk) {
                int e  = kk * 256 + tid;
                int aa = e / 320, r = e - aa * 320;
                int vv = r / 40,  c = r - vv * 40;
                rf[(long)(n * S + a0 + aa) * 6400 + (v0 + vv) * 40 + c] =
                    tf[vv * 320 + aa * 40 + c];
            }
        }
        // fused phase-1 partial sums over this v-tile
        #pragma unroll
        for (int j = 0; j < 5; ++j) {
            int p  = j * 256 + tid;         // 0..1279 (aa,u) pairs
            int aa = p / 160, u = p - aa * 160;
            int ag = a0 + aa;
            #pragma unroll
            for (int vv = 0; vv < 8; ++vv) {
                float x = tile[vv * 1280 + aa * 160 + u];
                int vg = v0 + vv;
                bool excl = (vg == ag) || (vg == u);
                acc[j] += excl ? 0.f : (sp_f(x) - LN2);
            }
        }
    }
    #pragma unroll
    for (int j = 0; j < 5; ++j) {
        int p  = j * 256 + tid;
        int aa = p / 160, u = p - aa * 160;
        atomicAdd(&db1[(n * S + a0 + aa) * S + u], acc[j]);
    }
}

// ---- phases 2/3: per (q,a,n) block, read slab-local tiles from R
template<int PHASE>
__global__ __launch_bounds__(256)
void bp_phase(const float* __restrict__ r_sib,
              const float* __restrict__ r_cop,
              const float* __restrict__ r_grd,
              const float* __restrict__ s_edge,
              const float* __restrict__ db1g,
              const float* __restrict__ db2g,
              float* __restrict__ db_out,
              float* __restrict__ outp)
{
    const float LN2 = 0.6931471805599453f;
    int q = blockIdx.x;          // 0..4 column-block
    int a = blockIdx.y;
    int n = blockIdx.z;
    int slice = n * S + a;
    int u0 = q * 32;
    int tid = threadIdx.x;
    int uj  = tid & 31;
    int vs  = tid >> 5;          // 0..7
    int ug  = u0 + uj;

    __shared__ float ldsA[80 * 32];    // A[v][u] chunk (10 KB)
    __shared__ float ldsB[32 * 81];    // B[u][v] chunk, stride 81 (10.1 KB)
    __shared__ float db1l[S];
    __shared__ float db2l[S];
    __shared__ float accS[256];
    __shared__ float Eu[32];

    if (tid < S) {
        db1l[tid] = db1g[slice * S + tid];
        if (PHASE >= 3) db2l[tid] = db2g[slice * S + tid];
    }
    if (tid < 32) Eu[tid] = s_edge[n * S2 + (u0 + tid) * S + a];

    const long slab = (long)slice * SLAB;
    float acc = 0.f;

    for (int t = 0; t < 3; ++t) {
        const float* rT = (t == 0) ? r_sib : (t == 1) ? r_cop : r_grd;
        const float4* rf = (const float4*)(rT + slab);
        for (int h = 0; h < 2; ++h) {
            int v0 = h * 80;
            __syncthreads();
            // stage A: R[v0+row][u0 + 4*c4], 80 rows x 8 float4 (col-block, slab-local)
            for (int e = tid; e < 640; e += 256) {
                int row = e >> 3, c4 = e & 7;
                ((float4*)ldsA)[e] = rf[(v0 + row) * 40 + q * 8 + c4];
            }
            // stage B: R[u0+r][v0 + 4*c], 32 rows x 20 float4 (row-block, contiguous 10 KB)
            for (int e = tid; e < 640; e += 256) {
                int r = e / 20, c = e - r * 20;
                float4 val = rf[(u0 + r) * 40 + h * 20 + c];
                int lb = r * 81 + c * 4;
                ldsB[lb]     = val.x;
                ldsB[lb + 1] = val.y;
                ldsB[lb + 2] = val.z;
                ldsB[lb + 3] = val.w;
            }
            __syncthreads();
            if (PHASE == 2) {
                #pragma unroll
                for (int k = 0; k < 10; ++k) {
                    int vi = v0 + k * 8 + vs;
                    float A  = ldsA[k * 256 + tid];        // p(v,u)
                    float Bv = ldsB[uj * 81 + k * 8 + vs]; // p(u,v)
                    float x  = db1l[vi] - (sp_f(Bv) - LN2);
                    float c  = sp_f(x + A) - sp_f(x);      // d2[u,v]
                    bool excl = (vi == a) || (vi == ug);
                    acc += excl ? 0.f : c;
                }
            } else {
                float db1u = db1l[ug] + LN2;
                #pragma unroll
                for (int k = 0; k < 10; ++k) {
                    int vi = v0 + k * 8 + vs;
                    float A  = ldsA[k * 256 + tid];        // p(v,u)
                    float Bv = ldsB[uj * 81 + k * 8 + vs]; // p(u,v)
                    float z  = db1u - sp_f(A);             // db1[u] - d1[u,v]
                    float d2 = sp_f(z + Bv) - sp_f(z);     // d2[v,u]
                    float y  = db2l[vi] - d2;
                    float c  = sp_f(y + A) - sp_f(y);      // d3[u,v]
                    bool excl = (vi == a) || (vi == ug);
                    acc += excl ? 0.f : c;
                }
            }
        }
    }

    accS[tid] = acc;
    __syncthreads();
    if (tid < 32) {
        float s = Eu[tid];
        #pragma unroll
        for (int j = 0; j < 8; ++j) s += accS[j * 32 + tid];
        if (PHASE == 2) {
            db_out[slice * S + u0 + tid] = s;
        } else {
            float sg = 1.f / (1.f + __expf(-s));
            long ob = ((long)(n * S + u0 + tid) * S + a) * 2;
            outp[ob]     = 1.f - sg;
            outp[ob + 1] = sg;
        }
    }
}

extern "C" void kernel_launch(void* const* d_in, const int* in_sizes, int n_in,
                              void* d_out, int out_size, void* d_ws, size_t ws_size,
                              hipStream_t stream) {
    const float* s_edge = (const float*)d_in[0];
    const float* s_sib  = (const float*)d_in[1];
    const float* s_cop  = (const float*)d_in[2];
    const float* s_grd  = (const float*)d_in[3];
    float* outp  = (float*)d_out;
    float* db1   = (float*)d_ws;           // 51200 floats
    float* db2   = db1 + 2 * S * S;        // 51200 floats
    float* r_sib = db2 + 2 * S * S;        // 3 x 8,192,000 floats (~98.3 MB)
    float* r_cop = r_sib + TSZ;
    float* r_grd = r_cop + TSZ;

    k_init<<<dim3(S, 2), 160, 0, stream>>>(s_edge, db1);
    k_transpose<<<dim3(20, 20, 2), 256, 0, stream>>>(s_sib, s_cop, s_grd,
                                                     r_sib, r_cop, r_grd, db1);
    dim3 grid(5, S, 2);
    bp_phase<2><<<grid, 256, 0, stream>>>(r_sib, r_cop, r_grd, s_edge,
                                          db1, nullptr, db2, nullptr);
    bp_phase<3><<<grid, 256, 0, stream>>>(r_sib, r_cop, r_grd, s_edge,
                                          db1, db2, nullptr, outp);
}

// Round 5
// 243.764 us; speedup vs baseline: 1.3016x; 1.3016x over previous
//
#include <hip/hip_runtime.h>
#include <hip/hip_fp16.h>

// LBP semantic dependency, channel-difference form, base-2 domain.
//   d'(x,p) = sp(x+p) - sp(x);  db[a,u] = edge + sum_{v!=a,u} sum_t d'-terms
// We store tp = e^p as fp16 (threshold 2e-2; fp16 rel err 5e-4 -> output err
// ~3e-3). All db quantities are in units of ln2 (base-2):
//   sp2t(tp) = log2(1+tp);  F(x,tp) = log2(1+2^x*tp) - log2(1+2^x)
// Phase 1 is fused into the sequential convert pass (register partials over
// v-chunks); exclusions (v==a, v==u) are pre-subtracted by tiny init kernels
// so the heavy inner loops are maskless sums over ALL v.
// R4 fixes: (1) B16 staging copied 4 halves into 8-half slots -> half the
// tile was uninitialized LDS (NaN source); (2) output exp2f(-s) overflows to
// inf for s < -127 -> inf*0 = NaN; clamp s to +-60 (sigmoid saturated).

#define S    160
#define S2   25600            // 160*160
#define S3   4096000          // 160^3 (per-n slab, elements)
#define TSZ  8192000          // per tensor elements (2*160^3)
#define C2E  1.4426950408889634f

__device__ __forceinline__ float cdb(float x) {
    return fminf(fmaxf(x, -100.f), 100.f);   // keeps exp2 finite; F saturated anyway
}
__device__ __forceinline__ float sp2t(float tp) { return log2f(1.f + tp); }
__device__ __forceinline__ float Ff(float x, float tp) {
    float tx = exp2f(x);                      // |x| <= ~117 -> finite
    return log2f(1.f + tx * tp) - log2f(1.f + tx);
}

// ---- pass 1: sequential read s_t, write tp16 (same layout), fused ph1 partials
__global__ __launch_bounds__(640)
void k_pass1(const float* __restrict__ s_sib, const float* __restrict__ s_cop,
             const float* __restrict__ s_grd, __half* __restrict__ tp16,
             float* __restrict__ P)
{
    int c = blockIdx.x;   // v-chunk of 4: 0..39
    int n = blockIdx.y;   // 0..1
    int t = blockIdx.z;   // 0..2
    const float* sT = (t == 0) ? s_sib : (t == 1) ? s_cop : s_grd;
    int tid = threadIdx.x;
    float4 acc[10];
    #pragma unroll
    for (int s = 0; s < 10; ++s) acc[s] = make_float4(0.f, 0.f, 0.f, 0.f);
    for (int vl = 0; vl < 4; ++vl) {
        int v = c * 4 + vl;
        const float4* g = (const float4*)(sT + (long)(n * S + v) * S2);
        uint2* o = (uint2*)(tp16 + (long)t * TSZ + (long)n * S3 + (long)v * S2);
        #pragma unroll
        for (int s = 0; s < 10; ++s) {
            int idx = s * 640 + tid;
            float4 p = g[idx];
            float t0 = exp2f(p.x * C2E), t1 = exp2f(p.y * C2E);
            float t2 = exp2f(p.z * C2E), t3 = exp2f(p.w * C2E);
            acc[s].x += log2f(1.f + t0); acc[s].y += log2f(1.f + t1);
            acc[s].z += log2f(1.f + t2); acc[s].w += log2f(1.f + t3);
            __half2 h01 = __floats2half2_rn(t0, t1);
            __half2 h23 = __floats2half2_rn(t2, t3);
            uint2 w; w.x = *(unsigned*)&h01; w.y = *(unsigned*)&h23;
            o[idx] = w;
        }
    }
    float4* Pf = (float4*)(P + (long)(t * 80 + c * 2 + n) * S2);
    #pragma unroll
    for (int s = 0; s < 10; ++s) Pf[s * 640 + tid] = acc[s];
}

// ---- reduce partials + edge + exclusion terms -> db1
__global__ __launch_bounds__(256)
void k_reduce1(const float* __restrict__ P, const float* __restrict__ s_edge,
               const __half* __restrict__ tp16, float* __restrict__ db1)
{
    int flat = blockIdx.x * 256 + threadIdx.x;          // (n*S+a)*S+u
    int u = flat % S; int rest = flat / S; int a = rest % S; int n = rest / S;
    float s = 0.f;
    for (int t = 0; t < 3; ++t)
        for (int c = 0; c < 40; ++c)
            s += P[(long)(t * 80 + c * 2 + n) * S2 + a * S + u];
    float r = s_edge[n * S2 + u * S + a] * C2E + s - 480.f;   // -1 per (t,v): 3*160
    for (int t = 0; t < 3; ++t) {
        const __half* tp = tp16 + (long)t * TSZ + (long)n * S3;
        float tpa = __half2float(tp[(long)a * S2 + a * S + u]);   // tp(v=a, u)
        r -= (sp2t(tpa) - 1.f);
        if (u != a) {
            float tpu = __half2float(tp[(long)u * S2 + a * S + u]); // tp(u,u)
            r -= (sp2t(tpu) - 1.f);
        }
    }
    db1[flat] = r;
}

// ---- di2 = edge - phase2 exclusion terms
__global__ __launch_bounds__(256)
void k_init2(const float* __restrict__ s_edge, const __half* __restrict__ tp16,
             const float* __restrict__ db1, float* __restrict__ di2)
{
    int flat = blockIdx.x * 256 + threadIdx.x;
    int u = flat % S; int rest = flat / S; int a = rest % S; int n = rest / S;
    int slice = n * S + a;
    float db1a = cdb(db1[slice * S + a]) + 1.f;
    float db1u = cdb(db1[slice * S + u]) + 1.f;
    float sum = 0.f;
    for (int t = 0; t < 3; ++t) {
        const __half* tp = tp16 + (long)t * TSZ + (long)n * S3;
        float tpa  = __half2float(tp[(long)a * S2 + a * S + u]);  // tp(v=a, u)
        float tpba = __half2float(tp[(long)u * S2 + a * S + a]);  // tp(u, v=a)
        sum += Ff(db1a - sp2t(tpba), tpa);                        // C2(v=a)
        if (u != a) {
            float tpu = __half2float(tp[(long)u * S2 + a * S + u]);
            sum += Ff(db1u - sp2t(tpu), tpu);                     // C2(v=u)
        }
    }
    di2[flat] = s_edge[n * S2 + u * S + a] * C2E - sum;
}

// ---- di3 = edge - phase3 exclusion terms
__global__ __launch_bounds__(256)
void k_init3(const float* __restrict__ s_edge, const __half* __restrict__ tp16,
             const float* __restrict__ db1, const float* __restrict__ db2,
             float* __restrict__ di3)
{
    int flat = blockIdx.x * 256 + threadIdx.x;
    int u = flat % S; int rest = flat / S; int a = rest % S; int n = rest / S;
    int slice = n * S + a;
    float db1u = cdb(db1[slice * S + u]) + 1.f;
    float db2a = cdb(db2[slice * S + a]);
    float db2u = cdb(db2[slice * S + u]);
    float sum = 0.f;
    for (int t = 0; t < 3; ++t) {
        const __half* tp = tp16 + (long)t * TSZ + (long)n * S3;
        float tpa  = __half2float(tp[(long)a * S2 + a * S + u]);  // tp(v=a, u)
        float tpba = __half2float(tp[(long)u * S2 + a * S + a]);  // tp(u, v=a)
        float d2vu = Ff(db1u - sp2t(tpa), tpba);
        sum += Ff(db2a - d2vu, tpa);                              // C3(v=a)
        if (u != a) {
            float tpu = __half2float(tp[(long)u * S2 + a * S + u]);
            float d2  = Ff(db1u - sp2t(tpu), tpu);
            sum += Ff(db2u - d2, tpu);                            // C3(v=u)
        }
    }
    di3[flat] = s_edge[n * S2 + u * S + a] * C2E - sum;
}

// ---- phase 2: db2[u] = di2[u] + sum_{t, all v} F(db1p[v]-sp2t(tpB), tpA)
__global__ __launch_bounds__(256)
void k_ph2(const __half* __restrict__ tp16, const float* __restrict__ db1,
           const float* __restrict__ di2, float* __restrict__ db2)
{
    int bid = blockIdx.x;
    int slice = bid % 320;      // same-slice blocks -> same XCD (320 % 8 == 0)
    int q = bid / 320;
    int a = slice % S, n = slice / S;
    int u0 = q * 32;
    int tid = threadIdx.x;
    int uj = tid & 31, vs = tid >> 5;
    __shared__ __half A16[S * 32];      // tp(v,u) for u in block   (10 KB)
    __shared__ __half B16[32 * 164];    // tp(u,v), stride 164      (10.5 KB)
    __shared__ float db1l[S];
    __shared__ float accS[256];
    if (tid < S) db1l[tid] = cdb(db1[slice * S + tid]) + 1.f;
    float acc = 0.f;
    const long bh = (long)n * S3 + (long)a * S;
    for (int t = 0; t < 3; ++t) {
        const __half* tp = tp16 + (long)t * TSZ + bh;
        __syncthreads();
        for (int e = tid; e < 640; e += 256) {            // A: 160 rows x 4 chunks of 8 halves
            int row = e >> 2, c = e & 3;
            *(float4*)(&A16[e * 8]) = *(const float4*)(tp + (long)row * S2 + u0 + c * 8);
        }
        for (int e = tid; e < 1280; e += 256) {           // B: 32 rows x 40 chunks of 4 halves
            int r = e / 40, c = e - r * 40;
            *(uint2*)(&B16[r * 164 + c * 4]) = *(const uint2*)(tp + (long)(u0 + r) * S2 + c * 4);
        }
        __syncthreads();
        #pragma unroll
        for (int k = 0; k < 20; ++k) {
            int vi = k * 8 + vs;
            float tA = __half2float(A16[k * 256 + tid]);
            float tB = __half2float(B16[uj * 164 + vi]);
            acc += Ff(db1l[vi] - sp2t(tB), tA);
        }
    }
    accS[tid] = acc; __syncthreads();
    if (tid < 32) {
        float s = di2[slice * S + u0 + tid];
        #pragma unroll
        for (int j = 0; j < 8; ++j) s += accS[j * 32 + tid];
        db2[slice * S + u0 + tid] = s;
    }
}

// ---- phase 3 + output
__global__ __launch_bounds__(256)
void k_ph3(const __half* __restrict__ tp16, const float* __restrict__ db1,
           const float* __restrict__ db2, const float* __restrict__ di3,
           float* __restrict__ outp)
{
    int bid = blockIdx.x;
    int slice = bid % 320;
    int q = bid / 320;
    int a = slice % S, n = slice / S;
    int u0 = q * 32;
    int tid = threadIdx.x;
    int uj = tid & 31, vs = tid >> 5;
    int ug = u0 + uj;
    __shared__ __half A16[S * 32];
    __shared__ __half B16[32 * 164];
    __shared__ float db1l[S];
    __shared__ float db2l[S];
    __shared__ float accS[256];
    if (tid < S) {
        db1l[tid] = cdb(db1[slice * S + tid]) + 1.f;
        db2l[tid] = cdb(db2[slice * S + tid]);
    }
    float db1u = cdb(db1[slice * S + ug]) + 1.f;
    float acc = 0.f;
    const long bh = (long)n * S3 + (long)a * S;
    for (int t = 0; t < 3; ++t) {
        const __half* tp = tp16 + (long)t * TSZ + bh;
        __syncthreads();
        for (int e = tid; e < 640; e += 256) {
            int row = e >> 2, c = e & 3;
            *(float4*)(&A16[e * 8]) = *(const float4*)(tp + (long)row * S2 + u0 + c * 8);
        }
        for (int e = tid; e < 1280; e += 256) {
            int r = e / 40, c = e - r * 40;
            *(uint2*)(&B16[r * 164 + c * 4]) = *(const uint2*)(tp + (long)(u0 + r) * S2 + c * 4);
        }
        __syncthreads();
        #pragma unroll
        for (int k = 0; k < 20; ++k) {
            int vi = k * 8 + vs;
            float tA = __half2float(A16[k * 256 + tid]);
            float tB = __half2float(B16[uj * 164 + vi]);
            float d2 = Ff(db1u - sp2t(tA), tB);     // d2[v,u]
            acc += Ff(db2l[vi] - d2, tA);           // d3[u,v]
        }
    }
    accS[tid] = acc; __syncthreads();
    if (tid < 32) {
        float s = di3[slice * S + u0 + tid];
        #pragma unroll
        for (int j = 0; j < 8; ++j) s += accS[j * 32 + tid];
        float sc  = fminf(fmaxf(s, -60.f), 60.f);   // avoid exp2 overflow -> inf*0=NaN
        float tsg = exp2f(-sc);
        float r   = __fdividef(1.f, 1.f + tsg);
        long ob = ((long)(n * S + u0 + tid) * S + a) * 2;
        outp[ob]     = tsg * r;
        outp[ob + 1] = r;
    }
}

extern "C" void kernel_launch(void* const* d_in, const int* in_sizes, int n_in,
                              void* d_out, int out_size, void* d_ws, size_t ws_size,
                              hipStream_t stream) {
    const float* s_edge = (const float*)d_in[0];
    const float* s_sib  = (const float*)d_in[1];
    const float* s_cop  = (const float*)d_in[2];
    const float* s_grd  = (const float*)d_in[3];
    float* outp = (float*)d_out;

    __half* tp16 = (__half*)d_ws;                            // 49,152,000 B
    float*  P    = (float*)((char*)d_ws + 49152000);         // 24,576,000 B
    float*  db1  = P + 6144000;
    float*  di2  = db1 + 51200;
    float*  db2  = di2 + 51200;
    float*  di3  = db2 + 51200;                              // total ~74.6 MB

    k_pass1<<<dim3(40, 2, 3), 640, 0, stream>>>(s_sib, s_cop, s_grd, tp16, P);
    k_reduce1<<<200, 256, 0, stream>>>(P, s_edge, tp16, db1);
    k_init2<<<200, 256, 0, stream>>>(s_edge, tp16, db1, di2);
    k_ph2<<<1600, 256, 0, stream>>>(tp16, db1, di2, db2);
    k_init3<<<200, 256, 0, stream>>>(s_edge, tp16, db1, db2, di3);
    k_ph3<<<1600, 256, 0, stream>>>(tp16, db1, db2, di3, outp);
}

// Round 6
// 206.699 us; speedup vs baseline: 1.5349x; 1.1793x over previous
//
#include <hip/hip_runtime.h>
#include <hip/hip_fp16.h>

// LBP semantic dependency, channel-difference form, base-2 domain.
//   d'(x,p) = sp(x+p) - sp(x);  db[a,u] = edge + sum_{v!=a,u} sum_t d'-terms
// tp = e^p stored fp16, SLICE-MAJOR: tq[t][n][a][v][u] so each (n,a) slice's
// 160x160 tile is a contiguous 50KB slab (R5 was chunk-scatter bound).
// All db quantities in units of ln2: sp2t(tp)=log2(1+tp);
// F(x,tp)=log2(1+2^x*tp)-log2(1+2^x). Native v_exp/v_log via builtins
// (R5 used libm exp2f/log2f -> 3x VALU bloat from guard code).
// Phase-1 fused into pass1 (register partials); exclusions (v==a, v==u)
// pre-subtracted by tiny init kernels -> heavy loops are maskless.

#define S    160
#define S2   25600            // 160*160
#define S3   4096000          // 160^3 (per-n slab, elements)
#define TSZ  8192000          // per tensor elements (2*160^3)
#define C2E  1.4426950408889634f

__device__ __forceinline__ float fexp2(float x) { return __builtin_amdgcn_exp2f(x); }
__device__ __forceinline__ float flog2(float x) { return __builtin_amdgcn_logf(x); }
__device__ __forceinline__ float cdb(float x) {
    return fminf(fmaxf(x, -100.f), 100.f);   // keeps exp2 finite; F saturated anyway
}
__device__ __forceinline__ float sp2t(float tp) { return flog2(1.f + tp); }
__device__ __forceinline__ float Ff(float x, float tp) {
    float tx = fexp2(x);                      // |x| <= ~110 -> finite
    return flog2(1.f + tx * tp) - flog2(1.f + tx);
}
// tq element (v,u) of slice (n,a), tensor t:
#define TQ(tq, t, n, a, v, u) \
    (tq)[(long)(t) * TSZ + (long)(n) * S3 + (long)(a) * S2 + (v) * S + (u)]

// ---- pass 1: sequential read s_t, write tq (slice-major fp16), fused ph1 partials
__global__ __launch_bounds__(640)
void k_pass1(const float* __restrict__ s_sib, const float* __restrict__ s_cop,
             const float* __restrict__ s_grd, __half* __restrict__ tq,
             float* __restrict__ P)
{
    int c = blockIdx.x;   // v-chunk of 4: 0..39
    int n = blockIdx.y;   // 0..1
    int t = blockIdx.z;   // 0..2
    const float* sT = (t == 0) ? s_sib : (t == 1) ? s_cop : s_grd;
    int tid = threadIdx.x;
    float4 acc[10];
    #pragma unroll
    for (int s = 0; s < 10; ++s) acc[s] = make_float4(0.f, 0.f, 0.f, 0.f);
    uint2* o2 = (uint2*)(tq + (long)t * TSZ + (long)n * S3);  // uint2 = 4 halves
    for (int vl = 0; vl < 4; ++vl) {
        int v = c * 4 + vl;
        const float4* g = (const float4*)(sT + (long)(n * S + v) * S2);
        #pragma unroll
        for (int s = 0; s < 10; ++s) {
            int idx = s * 640 + tid;            // (a, uq): a=idx/40, uq=idx%40
            float4 p = g[idx];
            float t0 = fexp2(p.x * C2E), t1 = fexp2(p.y * C2E);
            float t2 = fexp2(p.z * C2E), t3 = fexp2(p.w * C2E);
            acc[s].x += flog2(1.f + t0); acc[s].y += flog2(1.f + t1);
            acc[s].z += flog2(1.f + t2); acc[s].w += flog2(1.f + t3);
            __half2 h01 = __floats2half2_rn(t0, t1);
            __half2 h23 = __floats2half2_rn(t2, t3);
            uint2 w; w.x = *(unsigned*)&h01; w.y = *(unsigned*)&h23;
            int a = idx / 40, uq = idx - a * 40;
            o2[a * 6400 + v * 40 + uq] = w;     // tq[n][a][v][uq*4..]
        }
    }
    float4* Pf = (float4*)(P + (long)(t * 80 + c * 2 + n) * S2);
    #pragma unroll
    for (int s = 0; s < 10; ++s) Pf[s * 640 + tid] = acc[s];
}

// ---- reduce partials + edge + exclusion terms -> db1
__global__ __launch_bounds__(256)
void k_reduce1(const float* __restrict__ P, const float* __restrict__ s_edge,
               const __half* __restrict__ tq, float* __restrict__ db1)
{
    int flat = blockIdx.x * 256 + threadIdx.x;          // (n*S+a)*S+u
    int u = flat % S; int rest = flat / S; int a = rest % S; int n = rest / S;
    float s = 0.f;
    for (int t = 0; t < 3; ++t)
        for (int c = 0; c < 40; ++c)
            s += P[(long)(t * 80 + c * 2 + n) * S2 + a * S + u];
    float r = s_edge[n * S2 + u * S + a] * C2E + s - 480.f;   // -1 per (t,v): 3*160
    for (int t = 0; t < 3; ++t) {
        float tpa = __half2float(TQ(tq, t, n, a, a, u));      // tp(v=a, u)
        r -= (sp2t(tpa) - 1.f);
        if (u != a) {
            float tpu = __half2float(TQ(tq, t, n, a, u, u));  // tp(u,u)
            r -= (sp2t(tpu) - 1.f);
        }
    }
    db1[flat] = r;
}

// ---- di2 = edge - phase2 exclusion terms
__global__ __launch_bounds__(256)
void k_init2(const float* __restrict__ s_edge, const __half* __restrict__ tq,
             const float* __restrict__ db1, float* __restrict__ di2)
{
    int flat = blockIdx.x * 256 + threadIdx.x;
    int u = flat % S; int rest = flat / S; int a = rest % S; int n = rest / S;
    int slice = n * S + a;
    float db1a = cdb(db1[slice * S + a]) + 1.f;
    float db1u = cdb(db1[slice * S + u]) + 1.f;
    float sum = 0.f;
    for (int t = 0; t < 3; ++t) {
        float tpa  = __half2float(TQ(tq, t, n, a, a, u));     // tp(v=a, u)
        float tpba = __half2float(TQ(tq, t, n, a, u, a));     // tp(u, v=a)
        sum += Ff(db1a - sp2t(tpba), tpa);                    // C2(v=a)
        if (u != a) {
            float tpu = __half2float(TQ(tq, t, n, a, u, u));
            sum += Ff(db1u - sp2t(tpu), tpu);                 // C2(v=u)
        }
    }
    di2[flat] = s_edge[n * S2 + u * S + a] * C2E - sum;
}

// ---- di3 = edge - phase3 exclusion terms
__global__ __launch_bounds__(256)
void k_init3(const float* __restrict__ s_edge, const __half* __restrict__ tq,
             const float* __restrict__ db1, const float* __restrict__ db2,
             float* __restrict__ di3)
{
    int flat = blockIdx.x * 256 + threadIdx.x;
    int u = flat % S; int rest = flat / S; int a = rest % S; int n = rest / S;
    int slice = n * S + a;
    float db1u = cdb(db1[slice * S + u]) + 1.f;
    float db2a = cdb(db2[slice * S + a]);
    float db2u = cdb(db2[slice * S + u]);
    float sum = 0.f;
    for (int t = 0; t < 3; ++t) {
        float tpa  = __half2float(TQ(tq, t, n, a, a, u));     // tp(v=a, u)
        float tpba = __half2float(TQ(tq, t, n, a, u, a));     // tp(u, v=a)
        float d2vu = Ff(db1u - sp2t(tpa), tpba);
        sum += Ff(db2a - d2vu, tpa);                          // C3(v=a)
        if (u != a) {
            float tpu = __half2float(TQ(tq, t, n, a, u, u));
            float d2  = Ff(db1u - sp2t(tpu), tpu);
            sum += Ff(db2u - d2, tpu);                        // C3(v=u)
        }
    }
    di3[flat] = s_edge[n * S2 + u * S + a] * C2E - sum;
}

// ---- phase 2: db2[u] = di2[u] + sum_{t, all v} F(db1[v]-sp2t(tp(u,v)), tp(v,u))
__global__ __launch_bounds__(256)
void k_ph2(const __half* __restrict__ tq, const float* __restrict__ db1,
           const float* __restrict__ di2, float* __restrict__ db2)
{
    int bid = blockIdx.x;
    int slice = bid % 320;      // same-slice blocks -> same XCD (320 % 8 == 0)
    int q = bid / 320;
    int a = slice % S, n = slice / S;
    int u0 = q * 32;
    int tid = threadIdx.x;
    int uj = tid & 31, vs = tid >> 5;
    __shared__ __half A16[S * 32];      // tp(v, u in block)        (10 KB)
    __shared__ __half B16[32 * 164];    // tp(u in block, v), s=164 (10.5 KB)
    __shared__ float db1l[S];
    __shared__ float accS[256];
    if (tid < S) db1l[tid] = cdb(db1[slice * S + tid]) + 1.f;
    float acc = 0.f;
    const __half* slab0 = tq + (long)n * S3 + (long)a * S2;   // 50KB contiguous/t
    for (int t = 0; t < 3; ++t) {
        const __half* slab = slab0 + (long)t * TSZ;
        __syncthreads();
        for (int e = tid; e < 640; e += 256) {    // A: 160 rows x 4 half8 (64B/row)
            int row = e >> 2, c = e & 3;
            *(float4*)(&A16[e * 8]) = *(const float4*)(slab + row * S + u0 + c * 8);
        }
        for (int e = tid; e < 1280; e += 256) {   // B: rows u0..u0+31 = 10KB contiguous
            int r = e / 40, c = e - r * 40;
            *(uint2*)(&B16[r * 164 + c * 4]) = *(const uint2*)(slab + (u0 + r) * S + c * 4);
        }
        __syncthreads();
        #pragma unroll
        for (int k = 0; k < 20; ++k) {
            int vi = k * 8 + vs;
            float tA = __half2float(A16[k * 256 + tid]);
            float tB = __half2float(B16[uj * 164 + vi]);
            acc += Ff(db1l[vi] - sp2t(tB), tA);
        }
    }
    accS[tid] = acc; __syncthreads();
    if (tid < 32) {
        float s = di2[slice * S + u0 + tid];
        #pragma unroll
        for (int j = 0; j < 8; ++j) s += accS[j * 32 + tid];
        db2[slice * S + u0 + tid] = s;
    }
}

// ---- phase 3 + output
__global__ __launch_bounds__(256)
void k_ph3(const __half* __restrict__ tq, const float* __restrict__ db1,
           const float* __restrict__ db2, const float* __restrict__ di3,
           float* __restrict__ outp)
{
    int bid = blockIdx.x;
    int slice = bid % 320;
    int q = bid / 320;
    int a = slice % S, n = slice / S;
    int u0 = q * 32;
    int tid = threadIdx.x;
    int uj = tid & 31, vs = tid >> 5;
    int ug = u0 + uj;
    __shared__ __half A16[S * 32];
    __shared__ __half B16[32 * 164];
    __shared__ float db1l[S];
    __shared__ float db2l[S];
    __shared__ float accS[256];
    if (tid < S) {
        db1l[tid] = cdb(db1[slice * S + tid]) + 1.f;
        db2l[tid] = cdb(db2[slice * S + tid]);
    }
    float db1u = cdb(db1[slice * S + ug]) + 1.f;
    float acc = 0.f;
    const __half* slab0 = tq + (long)n * S3 + (long)a * S2;
    for (int t = 0; t < 3; ++t) {
        const __half* slab = slab0 + (long)t * TSZ;
        __syncthreads();
        for (int e = tid; e < 640; e += 256) {
            int row = e >> 2, c = e & 3;
            *(float4*)(&A16[e * 8]) = *(const float4*)(slab + row * S + u0 + c * 8);
        }
        for (int e = tid; e < 1280; e += 256) {
            int r = e / 40, c = e - r * 40;
            *(uint2*)(&B16[r * 164 + c * 4]) = *(const uint2*)(slab + (u0 + r) * S + c * 4);
        }
        __syncthreads();
        #pragma unroll
        for (int k = 0; k < 20; ++k) {
            int vi = k * 8 + vs;
            float tA = __half2float(A16[k * 256 + tid]);
            float tB = __half2float(B16[uj * 164 + vi]);
            float d2 = Ff(db1u - sp2t(tA), tB);     // d2[v,u]
            acc += Ff(db2l[vi] - d2, tA);           // d3[u,v]
        }
    }
    accS[tid] = acc; __syncthreads();
    if (tid < 32) {
        float s = di3[slice * S + u0 + tid];
        #pragma unroll
        for (int j = 0; j < 8; ++j) s += accS[j * 32 + tid];
        float sc  = fminf(fmaxf(s, -60.f), 60.f);   // avoid exp2 overflow -> inf*0=NaN
        float tsg = fexp2(-sc);
        float r   = __fdividef(1.f, 1.f + tsg);
        long ob = ((long)(n * S + u0 + tid) * S + a) * 2;
        outp[ob]     = tsg * r;
        outp[ob + 1] = r;
    }
}

extern "C" void kernel_launch(void* const* d_in, const int* in_sizes, int n_in,
                              void* d_out, int out_size, void* d_ws, size_t ws_size,
                              hipStream_t stream) {
    const float* s_edge = (const float*)d_in[0];
    const float* s_sib  = (const float*)d_in[1];
    const float* s_cop  = (const float*)d_in[2];
    const float* s_grd  = (const float*)d_in[3];
    float* outp = (float*)d_out;

    __half* tq  = (__half*)d_ws;                             // 49,152,000 B
    float*  P   = (float*)((char*)d_ws + 49152000);          // 24,576,000 B
    float*  db1 = P + 6144000;
    float*  di2 = db1 + 51200;
    float*  db2 = di2 + 51200;
    float*  di3 = db2 + 51200;                               // total ~74.6 MB

    k_pass1<<<dim3(40, 2, 3), 640, 0, stream>>>(s_sib, s_cop, s_grd, tq, P);
    k_reduce1<<<200, 256, 0, stream>>>(P, s_edge, tq, db1);
    k_init2<<<200, 256, 0, stream>>>(s_edge, tq, db1, di2);
    k_ph2<<<1600, 256, 0, stream>>>(tq, db1, di2, db2);
    k_init3<<<200, 256, 0, stream>>>(s_edge, tq, db1, db2, di3);
    k_ph3<<<1600, 256, 0, stream>>>(tq, db1, db2, di3, outp);
}